// Round 3
// baseline (669.571 us; speedup 1.0000x reference)
//
#include <hip/hip_runtime.h>
#include <math.h>

#define U_   100000
#define I_   50000
#define NG_  20000
#define D_   64
#define G_   20
#define B_   16384
#define HGE  96     // (D + 2D)/2
#define D2   128
#define D3   192

struct alignas(16) WaveSmem {
    int   sidx[G_];   // 80 B   (offset 0)
    float ie[D_];     // offset 80   (16B aligned)
    float hb[D_];     // offset 336
    float gz0[D_];    // offset 592
    float t1[HGE];    // offset 848
    float tv[16];     // offset 1232
    float sc[G_];     // offset 1296
    float gef[D_];    // offset 1376
};                    // total 1632 B

__global__ __launch_bounds__(256) void vargr_fused_kernel(
    const int*   __restrict__ group_inputs,
    const int*   __restrict__ item_inputs,
    const int*   __restrict__ group_members,
    const float* __restrict__ eps,
    const float* __restrict__ user_emb,
    const float* __restrict__ item_emb,
    const float* __restrict__ ue_w1, const float* __restrict__ ue_b1,
    const float* __restrict__ ue_w2, const float* __restrict__ ue_b2,
    const float* __restrict__ ge_w1, const float* __restrict__ ge_b1,
    const float* __restrict__ ge_w2, const float* __restrict__ ge_b2,
    const float* __restrict__ at_w1, const float* __restrict__ at_b1,
    const float* __restrict__ at_w2, const float* __restrict__ at_b2,
    const float* __restrict__ pr_w1, const float* __restrict__ pr_b1,
    const float* __restrict__ pr_w2, const float* __restrict__ pr_b2,
    float* __restrict__ out, int nb)
{
    __shared__ WaveSmem sm[4];
    const int tid = threadIdx.x;
    const int w   = tid >> 6;   // wave id within block
    const int j   = tid & 63;   // lane id
    const int b   = blockIdx.x * 4 + w;   // batch element (grid exact: nb % 4 == 0)
    WaveSmem& S = sm[w];

    const int gid  = group_inputs[b];
    const int item = item_inputs[b];

    // ---- S0: member indices + item embedding into LDS ----
    if (j < G_) S.sidx[j] = group_members[gid * G_ + j];
    S.ie[j] = item_emb[(size_t)item * D_ + j];

    // W1 column j into registers (reused for all 20 members)
    float w1c[D_];
    #pragma unroll
    for (int k = 0; k < D_; ++k) w1c[k] = ue_w1[k * D_ + j];

    __syncthreads();

    // ---- S1: member MLP layer 1, mean of relu-hidden across members ----
    // mean(enc) = mean(relu(me@W1+b1)) @ W2 + b2  (W2 is linear -> pull mean inside)
    float hsum = 0.f;
    const float b1j = ue_b1[j];
    for (int g = 0; g < G_; ++g) {
        const float* mrow = user_emb + (size_t)S.sidx[g] * D_;
        float acc = b1j;
        #pragma unroll
        for (int kq = 0; kq < D_ / 4; ++kq) {
            const float4 m4 = *reinterpret_cast<const float4*>(mrow + kq * 4);
            acc += m4.x * w1c[kq * 4 + 0];
            acc += m4.y * w1c[kq * 4 + 1];
            acc += m4.z * w1c[kq * 4 + 2];
            acc += m4.w * w1c[kq * 4 + 3];
        }
        hsum += fmaxf(acc, 0.f);
    }
    S.hb[j] = hsum * (1.f / G_);
    __syncthreads();

    // ---- S2: layer 2 (hbar @ W2 + b2), relu -> gz0 ; also item part of attention hidden ----
    {
        float acc = ue_b2[j];
        #pragma unroll
        for (int kq = 0; kq < D_ / 4; ++kq) {
            const float4 h4 = *reinterpret_cast<const float4*>(&S.hb[kq * 4]);
            acc += h4.x * ue_w2[(kq * 4 + 0) * D_ + j];
            acc += h4.y * ue_w2[(kq * 4 + 1) * D_ + j];
            acc += h4.z * ue_w2[(kq * 4 + 2) * D_ + j];
            acc += h4.w * ue_w2[(kq * 4 + 3) * D_ + j];
        }
        S.gz0[j] = fmaxf(acc, 0.f);
    }
    if (j < 16) {
        // tv[u] = at_b1[u] + sum_k ie[k] * at_w1[64+k][u]
        float acc = at_b1[j];
        #pragma unroll 8
        for (int k = 0; k < D_; ++k)
            acc += S.ie[k] * at_w1[(D_ + k) * 16 + j];
        S.tv[j] = acc;
    }
    __syncthreads();

    // ---- S3: group encoder layer 1: t1 = relu(gz0 @ ge_w1 + ge_b1), 96 cols ----
    #pragma unroll
    for (int half = 0; half < 2; ++half) {
        const int jj = j + half * 64;
        if (jj < HGE) {
            float acc = ge_b1[jj];
            #pragma unroll
            for (int kq = 0; kq < D_ / 4; ++kq) {
                const float4 g4 = *reinterpret_cast<const float4*>(&S.gz0[kq * 4]);
                acc += g4.x * ge_w1[(kq * 4 + 0) * HGE + jj];
                acc += g4.y * ge_w1[(kq * 4 + 1) * HGE + jj];
                acc += g4.z * ge_w1[(kq * 4 + 2) * HGE + jj];
                acc += g4.w * ge_w1[(kq * 4 + 3) * HGE + jj];
            }
            S.t1[jj] = fmaxf(acc, 0.f);
        }
    }
    __syncthreads();

    // ---- S4: group encoder layer 2 -> z_mu (col j), z_sigma (col j+64); attention scores ----
    float mu, sig;
    {
        float a0 = ge_b2[j];
        float a1 = ge_b2[j + 64];
        #pragma unroll
        for (int kq = 0; kq < HGE / 4; ++kq) {
            const float4 t4 = *reinterpret_cast<const float4*>(&S.t1[kq * 4]);
            a0 += t4.x * ge_w2[(kq * 4 + 0) * D2 + j];
            a0 += t4.y * ge_w2[(kq * 4 + 1) * D2 + j];
            a0 += t4.z * ge_w2[(kq * 4 + 2) * D2 + j];
            a0 += t4.w * ge_w2[(kq * 4 + 3) * D2 + j];
            a1 += t4.x * ge_w2[(kq * 4 + 0) * D2 + 64 + j];
            a1 += t4.y * ge_w2[(kq * 4 + 1) * D2 + 64 + j];
            a1 += t4.z * ge_w2[(kq * 4 + 2) * D2 + 64 + j];
            a1 += t4.w * ge_w2[(kq * 4 + 3) * D2 + 64 + j];
        }
        mu  = a0;
        sig = 0.1f + 0.9f / (1.f + expf(-a1));
    }
    {
        // 4 members in parallel (16 lanes each), 5 rounds
        const int u = j & 15;
        const int q = j >> 4;
        const float aw2u = at_w2[u];
        #pragma unroll
        for (int gg = 0; gg < 5; ++gg) {
            const int g = q + gg * 4;
            const float* mrow = user_emb + (size_t)S.sidx[g] * D_;
            float hh = S.tv[u];
            #pragma unroll
            for (int kq = 0; kq < D_ / 4; ++kq) {
                const float4 m4 = *reinterpret_cast<const float4*>(mrow + kq * 4);
                hh += m4.x * at_w1[(kq * 4 + 0) * 16 + u];
                hh += m4.y * at_w1[(kq * 4 + 1) * 16 + u];
                hh += m4.z * at_w1[(kq * 4 + 2) * 16 + u];
                hh += m4.w * at_w1[(kq * 4 + 3) * 16 + u];
            }
            float v = fmaxf(hh, 0.f) * aw2u;
            v += __shfl_xor(v, 1, 16);
            v += __shfl_xor(v, 2, 16);
            v += __shfl_xor(v, 4, 16);
            v += __shfl_xor(v, 8, 16);
            if (u == 0) S.sc[g] = v + at_b2[0];
        }
    }
    __syncthreads();

    // ---- S5: softmax over 20 member scores ----
    if (j < 32) {
        const float s = (j < G_) ? S.sc[j] : -INFINITY;
        float m = s;
        #pragma unroll
        for (int off = 16; off; off >>= 1) m = fmaxf(m, __shfl_xor(m, off, 32));
        const float e = (j < G_) ? expf(s - m) : 0.f;
        float sum = e;
        #pragma unroll
        for (int off = 16; off; off >>= 1) sum += __shfl_xor(sum, off, 32);
        if (j < G_) S.sc[j] = e / sum;
    }
    __syncthreads();

    // ---- S6: attention-weighted member sum + reparameterized group embedding ----
    {
        float ga = 0.f;
        #pragma unroll
        for (int g = 0; g < G_; ++g)
            ga += S.sc[g] * user_emb[(size_t)S.sidx[g] * D_ + j];
        const float gef = ga + mu + sig * eps[(size_t)b * D_ + j];
        S.gef[j] = gef;
    }
    __syncthreads();

    // ---- S7: predictor MLP on ncf = [gef*ie, gef, ie] (192) -> 8 -> 1 ----
    {
        const int uu = j & 7;
        const int c  = j >> 3;   // 8 chunks x 24 k
        float part = 0.f;
        #pragma unroll
        for (int kk = 0; kk < 24; ++kk) {
            const int k = c * 24 + kk;
            float x;
            if (k < 64)       x = S.gef[k] * S.ie[k];
            else if (k < 128) x = S.gef[k - 64];
            else              x = S.ie[k - 128];
            part += x * pr_w1[k * 8 + uu];
        }
        part += __shfl_xor(part, 8,  64);
        part += __shfl_xor(part, 16, 64);
        part += __shfl_xor(part, 32, 64);
        float h = fmaxf(part + pr_b1[uu], 0.f) * pr_w2[uu];
        h += __shfl_xor(h, 1, 64);
        h += __shfl_xor(h, 2, 64);
        h += __shfl_xor(h, 4, 64);
        if (j == 0) out[b] = 1.f / (1.f + expf(-(h + pr_b2[0])));
    }
}

extern "C" void kernel_launch(void* const* d_in, const int* in_sizes, int n_in,
                              void* d_out, int out_size, void* d_ws, size_t ws_size,
                              hipStream_t stream) {
    const int*   group_inputs  = (const int*)d_in[0];
    const int*   item_inputs   = (const int*)d_in[1];
    const int*   group_members = (const int*)d_in[2];
    const float* eps           = (const float*)d_in[3];
    const float* user_emb      = (const float*)d_in[4];
    const float* item_emb      = (const float*)d_in[5];
    const float* ue_w1 = (const float*)d_in[6];
    const float* ue_b1 = (const float*)d_in[7];
    const float* ue_w2 = (const float*)d_in[8];
    const float* ue_b2 = (const float*)d_in[9];
    const float* ge_w1 = (const float*)d_in[10];
    const float* ge_b1 = (const float*)d_in[11];
    const float* ge_w2 = (const float*)d_in[12];
    const float* ge_b2 = (const float*)d_in[13];
    const float* at_w1 = (const float*)d_in[14];
    const float* at_b1 = (const float*)d_in[15];
    const float* at_w2 = (const float*)d_in[16];
    const float* at_b2 = (const float*)d_in[17];
    const float* pr_w1 = (const float*)d_in[18];
    const float* pr_b1 = (const float*)d_in[19];
    const float* pr_w2 = (const float*)d_in[20];
    const float* pr_b2 = (const float*)d_in[21];
    float* out = (float*)d_out;

    const int nb = in_sizes[0];          // B = 16384, divisible by 4
    const int grid = nb / 4;

    vargr_fused_kernel<<<grid, 256, 0, stream>>>(
        group_inputs, item_inputs, group_members, eps, user_emb, item_emb,
        ue_w1, ue_b1, ue_w2, ue_b2, ge_w1, ge_b1, ge_w2, ge_b2,
        at_w1, at_b1, at_w2, at_b2, pr_w1, pr_b1, pr_w2, pr_b2,
        out, nb);
}

// Round 5
// 45.057 us; speedup vs baseline: 14.8604x; 14.8604x over previous
//
#include <hip/hip_runtime.h>
#include <math.h>

#define D_   64
#define G_   20
#define BT   16     // batch elements per block
#define XPAD 132    // xbuf row stride in floats (132%32=4 -> 2-way bank alias, free)

typedef __attribute__((ext_vector_type(8))) short bf8;   // 8 bf16 (4 VGPRs)
typedef __attribute__((ext_vector_type(4))) float f4;    // MFMA accumulator

__device__ __forceinline__ short f2bf(float f){
    union { float f; unsigned u; } c; c.f = f;
    unsigned r = c.u + 0x7fffu + ((c.u >> 16) & 1u);   // RNE
    return (short)(r >> 16);
}
__device__ __forceinline__ bf8 pack8(float4 a, float4 b){
    bf8 r;
    r[0]=f2bf(a.x); r[1]=f2bf(a.y); r[2]=f2bf(a.z); r[3]=f2bf(a.w);
    r[4]=f2bf(b.x); r[5]=f2bf(b.y); r[6]=f2bf(b.z); r[7]=f2bf(b.w);
    return r;
}

__global__ __launch_bounds__(256, 4) void vargr_mfma_kernel(
    const int*   __restrict__ group_inputs,
    const int*   __restrict__ item_inputs,
    const int*   __restrict__ group_members,
    const float* __restrict__ eps,
    const float* __restrict__ user_emb,
    const float* __restrict__ item_emb,
    const float* __restrict__ ue_w1, const float* __restrict__ ue_b1,
    const float* __restrict__ ue_w2, const float* __restrict__ ue_b2,
    const float* __restrict__ ge_w1, const float* __restrict__ ge_b1,
    const float* __restrict__ ge_w2, const float* __restrict__ ge_b2,
    const float* __restrict__ at_w1, const float* __restrict__ at_b1,
    const float* __restrict__ at_w2, const float* __restrict__ at_b2,
    const float* __restrict__ pr_w1, const float* __restrict__ pr_b1,
    const float* __restrict__ pr_w2, const float* __restrict__ pr_b2,
    float* __restrict__ out)
{
    // LDS: 10240 + 8448 + 8448 + 4096 + 4096 + 1024 + 1280 + 1280 = 38912 B (<40KB -> 4 blocks/CU)
    __shared__ unsigned short Wt[80*64];   // [ue_w1 | at_w1_top] transposed, bf16, XOR-swizzled
    __shared__ float xA[BT*XPAD];          // activation ping
    __shared__ float xB[BT*XPAD];          // activation pong
    __shared__ float ieb[BT*64];           // item embeddings
    __shared__ float gefb[BT*64];          // attention-weighted member sum
    __shared__ float tvs[BT*16];           // item-side attention hidden (+at_b1)
    __shared__ float wsm[BT*G_];           // scores -> softmax weights
    __shared__ int   sidx[BT*G_];          // member indices

    const int tid = threadIdx.x;
    const int w = tid >> 6, l = tid & 63;
    const int bbase = blockIdx.x * BT;

    // ---- stage combined weight Wt[col][k] (bf16, swizzled), all 256 threads ----
    for (int e = tid; e < 64*80; e += 256){
        int k = e / 80, col = e - k*80;
        float v = (col < 64) ? ue_w1[k*64 + col] : at_w1[k*16 + (col - 64)];
        int byte = col*128 + ( ((2*k) & ~15) ^ ((col & 7) << 4) ) + ((2*k) & 15);
        *(unsigned short*)((char*)Wt + byte) = (unsigned short)f2bf(v);
    }

    // ---- per-wave staging: item emb + member indices (wave w owns bb = 4w..4w+3) ----
    {
        int bb = 4*w + (l >> 4);
        int q  = l & 15;
        int item = item_inputs[bbase + bb];
        ((float4*)(ieb + bb*64))[q] = ((const float4*)(item_emb + (size_t)item*64))[q];
    }
    #pragma unroll
    for (int i = 0; i < 4; ++i){
        int bb = 4*w + i;
        if (l < G_){
            int gid = group_inputs[bbase + bb];
            sidx[bb*G_ + l] = group_members[gid*G_ + l];
        }
    }
    // ---- tv[bb][u] = at_b1[u] + ie . at_w1[64: ,u]  (same-wave LDS dep) ----
    {
        int bb = 4*w + (l >> 4);
        int u  = l & 15;
        float acc = at_b1[u];
        const float* ier = ieb + bb*64;
        #pragma unroll 8
        for (int k = 0; k < 64; ++k) acc += ier[k] * at_w1[(64 + k)*16 + u];
        tvs[bb*16 + u] = acc;
    }
    __syncthreads();   // Wt is the only cross-wave dependency above

    // ---- hoist member-GEMM B-fragments (10 x ds_read_b128, swizzled, conflict-free) ----
    bf8 bfr[5][2];
    #pragma unroll
    for (int nt = 0; nt < 5; ++nt)
        #pragma unroll
        for (int kt = 0; kt < 2; ++kt){
            int col  = nt*16 + (l & 15);
            int byte = col*128 + ( (kt*64 + (l >> 4)*16) ^ ((col & 7) << 4) );
            bfr[nt][kt] = *(const bf8*)((const char*)Wt + byte);
        }
    float bias1[4];
    #pragma unroll
    for (int nt = 0; nt < 4; ++nt) bias1[nt] = ue_b1[nt*16 + (l & 15)];
    const float aw2  = at_w2[l & 15];
    const float atb2 = at_b2[0];

    // ================= Phase 1: per-batch member GEMM + pooling + attention =================
    #pragma unroll 1
    for (int i = 0; i < 4; ++i){
        const int bb = 4*w + i;
        const int* sx = sidx + bb*G_;
        float msum[4] = {0.f, 0.f, 0.f, 0.f};

        #pragma unroll
        for (int mt = 0; mt < 2; ++mt){
            // A-fragment: row = mt*16 + (lane&15), k = (lane>>4)*8 + [0..7] (+32 for kt=1)
            int r = mt*16 + (l & 15);
            int g = (r < G_) ? r : (G_ - 1);                   // pad rows duplicate row 19
            const float4* p = (const float4*)(user_emb + (size_t)sx[g]*64) + ((l >> 4)*2);
            bf8 a0 = pack8(p[0], p[1]);                        // k 0..31 slice
            bf8 a1 = pack8(p[8], p[9]);                        // k 32..63 slice

            f4 acc[5];
            #pragma unroll
            for (int nt = 0; nt < 5; ++nt) acc[nt] = (f4){0.f, 0.f, 0.f, 0.f};
            #pragma unroll
            for (int nt = 0; nt < 5; ++nt){
                acc[nt] = __builtin_amdgcn_mfma_f32_16x16x32_bf16(a0, bfr[nt][0], acc[nt], 0, 0, 0);
                acc[nt] = __builtin_amdgcn_mfma_f32_16x16x32_bf16(a1, bfr[nt][1], acc[nt], 0, 0, 0);
            }

            // H1 (cols 0..63): accumulate column-sums of relu over valid rows only
            #pragma unroll
            for (int nt = 0; nt < 4; ++nt){
                float rs = 0.f;
                #pragma unroll
                for (int rr = 0; rr < 4; ++rr) rs += fmaxf(acc[nt][rr] + bias1[nt], 0.f);
                if (mt == 1 && (l >> 4) != 0) rs = 0.f;        // tile1 valid rows: 16..19 (group 0)
                msum[nt] += rs;
            }
            // scores (cols 64..79): per-row sum over 16 hidden units
            {
                float tvv = tvs[bb*16 + (l & 15)];
                float vv[4];
                #pragma unroll
                for (int rr = 0; rr < 4; ++rr) vv[rr] = fmaxf(acc[4][rr] + tvv, 0.f) * aw2;
                #pragma unroll
                for (int rr = 0; rr < 4; ++rr){
                    vv[rr] += __shfl_xor(vv[rr], 1);
                    vv[rr] += __shfl_xor(vv[rr], 2);
                    vv[rr] += __shfl_xor(vv[rr], 4);
                    vv[rr] += __shfl_xor(vv[rr], 8);
                }
                if ((l & 15) == 0 && (mt == 0 || (l >> 4) == 0)){
                    #pragma unroll
                    for (int rr = 0; rr < 4; ++rr)
                        wsm[bb*G_ + mt*16 + (l >> 4)*4 + rr] = vv[rr] + atb2;
                }
            }
        }

        // finish mean -> hbar row in xA
        #pragma unroll
        for (int nt = 0; nt < 4; ++nt){
            msum[nt] += __shfl_xor(msum[nt], 16);
            msum[nt] += __shfl_xor(msum[nt], 32);
            if ((l >> 4) == nt) xA[bb*XPAD + nt*16 + (l & 15)] = msum[nt] * (1.f / G_);
        }

        // softmax over the 20 scores (wave-local, width-32 shuffles)
        {
            float sval = (l < G_) ? wsm[bb*G_ + l] : -3.0e38f;
            float mx = sval;
            mx = fmaxf(mx, __shfl_xor(mx, 1, 32));
            mx = fmaxf(mx, __shfl_xor(mx, 2, 32));
            mx = fmaxf(mx, __shfl_xor(mx, 4, 32));
            mx = fmaxf(mx, __shfl_xor(mx, 8, 32));
            mx = fmaxf(mx, __shfl_xor(mx, 16, 32));
            float e = (l < G_) ? expf(sval - mx) : 0.f;
            float sm = e;
            sm += __shfl_xor(sm, 1, 32);
            sm += __shfl_xor(sm, 2, 32);
            sm += __shfl_xor(sm, 4, 32);
            sm += __shfl_xor(sm, 8, 32);
            sm += __shfl_xor(sm, 16, 32);
            if (l < G_) wsm[bb*G_ + l] = e / sm;
        }

        // attention-weighted member sum (coalesced 256B row loads, weight broadcast)
        {
            float ga = 0.f;
            #pragma unroll
            for (int g = 0; g < G_; ++g)
                ga += wsm[bb*G_ + g] * user_emb[(size_t)sx[g]*64 + l];
            gefb[bb*64 + l] = ga;
        }
    }
    __syncthreads();

    // ================= Phase 2: group-MLP chain, M=16 (all block batches), N-split by wave =================
    // L1: X1 = relu(X0 @ ue_w2 + ue_b2) : 64 cols, wave w does cols [16w,16w+16)
    {
        int col = w*16 + (l & 15);
        f4 acc = (f4){0.f, 0.f, 0.f, 0.f};
        #pragma unroll
        for (int kt = 0; kt < 2; ++kt){
            const float* ap = xA + (l & 15)*XPAD + kt*32 + (l >> 4)*8;
            bf8 a = pack8(*(const float4*)ap, *(const float4*)(ap + 4));
            int k0 = kt*32 + (l >> 4)*8;
            bf8 bfrg;
            #pragma unroll
            for (int q = 0; q < 8; ++q) bfrg[q] = f2bf(ue_w2[(k0 + q)*64 + col]);
            acc = __builtin_amdgcn_mfma_f32_16x16x32_bf16(a, bfrg, acc, 0, 0, 0);
        }
        float bs = ue_b2[col];
        #pragma unroll
        for (int rr = 0; rr < 4; ++rr)
            xB[(4*(l >> 4) + rr)*XPAD + col] = fmaxf(acc[rr] + bs, 0.f);
    }
    __syncthreads();

    // L2: X2 = relu(X1 @ ge_w1 + ge_b1) : 96 cols
    for (int t = w; t < 6; t += 4){
        int col = t*16 + (l & 15);
        f4 acc = (f4){0.f, 0.f, 0.f, 0.f};
        #pragma unroll
        for (int kt = 0; kt < 2; ++kt){
            const float* ap = xB + (l & 15)*XPAD + kt*32 + (l >> 4)*8;
            bf8 a = pack8(*(const float4*)ap, *(const float4*)(ap + 4));
            int k0 = kt*32 + (l >> 4)*8;
            bf8 bfrg;
            #pragma unroll
            for (int q = 0; q < 8; ++q) bfrg[q] = f2bf(ge_w1[(k0 + q)*96 + col]);
            acc = __builtin_amdgcn_mfma_f32_16x16x32_bf16(a, bfrg, acc, 0, 0, 0);
        }
        float bs = ge_b1[col];
        #pragma unroll
        for (int rr = 0; rr < 4; ++rr)
            xA[(4*(l >> 4) + rr)*XPAD + col] = fmaxf(acc[rr] + bs, 0.f);
    }
    __syncthreads();

    // L3: X3 = X2 @ ge_w2 + ge_b2 : 128 cols (raw; mu = cols 0..63, sigma-logit = 64..127)
    for (int t = w; t < 8; t += 4){
        int col = t*16 + (l & 15);
        f4 acc = (f4){0.f, 0.f, 0.f, 0.f};
        #pragma unroll
        for (int kt = 0; kt < 3; ++kt){
            const float* ap = xA + (l & 15)*XPAD + kt*32 + (l >> 4)*8;
            bf8 a = pack8(*(const float4*)ap, *(const float4*)(ap + 4));
            int k0 = kt*32 + (l >> 4)*8;
            bf8 bfrg;
            #pragma unroll
            for (int q = 0; q < 8; ++q) bfrg[q] = f2bf(ge_w2[(k0 + q)*128 + col]);
            acc = __builtin_amdgcn_mfma_f32_16x16x32_bf16(a, bfrg, acc, 0, 0, 0);
        }
        float bs = ge_b2[col];
        #pragma unroll
        for (int rr = 0; rr < 4; ++rr)
            xB[(4*(l >> 4) + rr)*XPAD + col] = acc[rr] + bs;
    }
    __syncthreads();

    // ================= Phase 3: reparameterize + predictor (wave-local) =================
    {
        float pa[8], pb_[8], pc_[8], pb1v[8], pw2v[8];
        #pragma unroll
        for (int u = 0; u < 8; ++u){
            pa[u]   = pr_w1[l*8 + u];            // k = l        (gef*ie part)
            pb_[u]  = pr_w1[(64 + l)*8 + u];     // k = 64 + l   (gef part)
            pc_[u]  = pr_w1[(128 + l)*8 + u];    // k = 128 + l  (ie part)
            pb1v[u] = pr_b1[u];
            pw2v[u] = pr_w2[u];
        }
        const float pb2v = pr_b2[0];

        #pragma unroll 1
        for (int i = 0; i < 4; ++i){
            int bb = 4*w + i;
            int b  = bbase + bb;
            float muv = xB[bb*XPAD + l];
            float sgr = xB[bb*XPAD + 64 + l];
            float sg  = 0.1f + 0.9f / (1.f + expf(-sgr));
            float gefv = gefb[bb*64 + l] + muv + sg * eps[(size_t)b*64 + l];
            float iev  = ieb[bb*64 + l];
            float x0 = gefv * iev;
            float pu[8];
            #pragma unroll
            for (int u = 0; u < 8; ++u) pu[u] = x0*pa[u] + gefv*pb_[u] + iev*pc_[u];
            #pragma unroll
            for (int off = 1; off < 64; off <<= 1){
                #pragma unroll
                for (int u = 0; u < 8; ++u) pu[u] += __shfl_xor(pu[u], off);
            }
            float hh = 0.f;
            #pragma unroll
            for (int u = 0; u < 8; ++u) hh += fmaxf(pu[u] + pb1v[u], 0.f) * pw2v[u];
            if (l == 0) out[b] = 1.f / (1.f + expf(-(hh + pb2v)));
        }
    }
}

extern "C" void kernel_launch(void* const* d_in, const int* in_sizes, int n_in,
                              void* d_out, int out_size, void* d_ws, size_t ws_size,
                              hipStream_t stream) {
    const int*   group_inputs  = (const int*)d_in[0];
    const int*   item_inputs   = (const int*)d_in[1];
    const int*   group_members = (const int*)d_in[2];
    const float* eps           = (const float*)d_in[3];
    const float* user_emb      = (const float*)d_in[4];
    const float* item_emb      = (const float*)d_in[5];
    const float* ue_w1 = (const float*)d_in[6];
    const float* ue_b1 = (const float*)d_in[7];
    const float* ue_w2 = (const float*)d_in[8];
    const float* ue_b2 = (const float*)d_in[9];
    const float* ge_w1 = (const float*)d_in[10];
    const float* ge_b1 = (const float*)d_in[11];
    const float* ge_w2 = (const float*)d_in[12];
    const float* ge_b2 = (const float*)d_in[13];
    const float* at_w1 = (const float*)d_in[14];
    const float* at_b1 = (const float*)d_in[15];
    const float* at_w2 = (const float*)d_in[16];
    const float* at_b2 = (const float*)d_in[17];
    const float* pr_w1 = (const float*)d_in[18];
    const float* pr_b1 = (const float*)d_in[19];
    const float* pr_w2 = (const float*)d_in[20];
    const float* pr_b2 = (const float*)d_in[21];
    float* out = (float*)d_out;

    const int nb = in_sizes[0];          // B = 16384, divisible by BT=16
    vargr_mfma_kernel<<<nb / BT, 256, 0, stream>>>(
        group_inputs, item_inputs, group_members, eps, user_emb, item_emb,
        ue_w1, ue_b1, ue_w2, ue_b2, ge_w1, ge_b1, ge_w2, ge_b2,
        at_w1, at_b1, at_w2, at_b2, pr_w1, pr_b1, pr_w2, pr_b2,
        out);
}

// Round 6
// 44.965 us; speedup vs baseline: 14.8909x; 1.0020x over previous
//
#include <hip/hip_runtime.h>
#include <hip/hip_bf16.h>
#include <math.h>

#define G_   20
#define BT   16

typedef __attribute__((ext_vector_type(8))) short bf8;   // 8 bf16
typedef __attribute__((ext_vector_type(4))) float f4;    // MFMA acc

// ws fragment-group bases (units of one 64-lane x 8-elem fragment group = 512 ushorts)
#define FMB  0      // [ue_w1 | at_w1_top]  5nt x 2kt = 10 groups
#define FAT  10     // at_w1 bottom         1nt x 2kt = 2
#define FUE2 12     // ue_w2                4nt x 2kt = 8
#define FGE1 20     // ge_w1                6nt x 2kt = 12
#define FGE2 32     // ge_w2                8nt x 3kt = 24
#define FPR  56     // pr_w1 (N padded 16)  1nt x 6kt = 6
#define FTOT 62

__device__ __forceinline__ unsigned cvt2(float x, float y){
    float2 f; f.x = x; f.y = y;
    __hip_bfloat162 h = __float22bfloat162_rn(f);     // v_cvt_pk_bf16_f32
    return *reinterpret_cast<unsigned*>(&h);
}
__device__ __forceinline__ unsigned short cvt1(float x){
    __hip_bfloat16 h = __float2bfloat16(x);
    return *reinterpret_cast<unsigned short*>(&h);
}
__device__ __forceinline__ bf8 pack8(float4 a, float4 b){
    union { bf8 v; unsigned u[4]; } t;
    t.u[0] = cvt2(a.x, a.y); t.u[1] = cvt2(a.z, a.w);
    t.u[2] = cvt2(b.x, b.y); t.u[3] = cvt2(b.z, b.w);
    return t.v;
}

// ---------------- prep: weights -> fragment-linear bf16 in ws ----------------
__global__ __launch_bounds__(256) void vargr_prep(
    const float* __restrict__ ue_w1, const float* __restrict__ ue_w2,
    const float* __restrict__ ge_w1, const float* __restrict__ ge_w2,
    const float* __restrict__ at_w1, const float* __restrict__ pr_w1,
    unsigned short* __restrict__ ws)
{
    int f = blockIdx.x * 256 + threadIdx.x;           // fragment id
    if (f >= FTOT * 64) return;
    int lane = f & 63, grp = f >> 6;
    int col = lane & 15;
    int q8  = (lane >> 4) * 8;
    float v[8];
    if (grp < FAT){                                   // combined member weights
        int g = grp - FMB; int nt = g >> 1; int k0 = (g & 1)*32 + q8; int c = nt*16 + col;
        #pragma unroll
        for (int q = 0; q < 8; ++q)
            v[q] = (c < 64) ? ue_w1[(k0+q)*64 + c] : at_w1[(k0+q)*16 + (c - 64)];
    } else if (grp < FUE2){                           // at_w1 bottom half
        int g = grp - FAT; int k0 = g*32 + q8;
        #pragma unroll
        for (int q = 0; q < 8; ++q) v[q] = at_w1[(64 + k0 + q)*16 + col];
    } else if (grp < FGE1){
        int g = grp - FUE2; int nt = g >> 1; int k0 = (g & 1)*32 + q8;
        #pragma unroll
        for (int q = 0; q < 8; ++q) v[q] = ue_w2[(k0+q)*64 + nt*16 + col];
    } else if (grp < FGE2){
        int g = grp - FGE1; int nt = g >> 1; int k0 = (g & 1)*32 + q8;
        #pragma unroll
        for (int q = 0; q < 8; ++q) v[q] = ge_w1[(k0+q)*96 + nt*16 + col];
    } else if (grp < FPR){
        int g = grp - FGE2; int nt = g / 3; int k0 = (g % 3)*32 + q8;
        #pragma unroll
        for (int q = 0; q < 8; ++q) v[q] = ge_w2[(k0+q)*128 + nt*16 + col];
    } else {
        int g = grp - FPR; int k0 = g*32 + q8;
        #pragma unroll
        for (int q = 0; q < 8; ++q) v[q] = (col < 8) ? pr_w1[(k0+q)*8 + col] : 0.f;
    }
    union { bf8 b; unsigned u[4]; } t;
    t.u[0] = cvt2(v[0], v[1]); t.u[1] = cvt2(v[2], v[3]);
    t.u[2] = cvt2(v[4], v[5]); t.u[3] = cvt2(v[6], v[7]);
    *reinterpret_cast<bf8*>(ws + (size_t)f * 8) = t.b;
}

// ---------------- main ----------------
__global__ __launch_bounds__(256, 4) void vargr_main(
    const int*   __restrict__ group_inputs,
    const int*   __restrict__ item_inputs,
    const int*   __restrict__ group_members,
    const float* __restrict__ eps,
    const float* __restrict__ user_emb,
    const float* __restrict__ item_emb,
    const float* __restrict__ ue_b1, const float* __restrict__ ue_b2,
    const float* __restrict__ ge_b1, const float* __restrict__ ge_b2,
    const float* __restrict__ at_b1, const float* __restrict__ at_w2,
    const float* __restrict__ at_b2, const float* __restrict__ pr_b1,
    const float* __restrict__ pr_w2, const float* __restrict__ pr_b2,
    const unsigned short* __restrict__ ws,
    float* __restrict__ out)
{
    // LDS budget: 4352+4352+4352+4096+1280+1280+8448 = 28160 B -> 5 blocks/CU
    __shared__ unsigned short xAh[BT*136];   // activations ping (bf16, 272B rows)
    __shared__ unsigned short xBh[BT*136];   // activations pong
    __shared__ float ieb[BT*68];             // item emb f32 (272B rows)
    __shared__ float gefb[BT*64];            // att-sum, then final gef
    __shared__ float wsm[BT*G_];             // scores -> softmax weights
    __shared__ int   sidx[BT*G_];
    __shared__ float x3u[BT*132];            // L3 raw f32; later aliased as ncf bf16 [16][200]

    const int tid = threadIdx.x;
    const int w = tid >> 6, l = tid & 63;
    const int lq = l >> 4, lr = l & 15;
    const int bbase = blockIdx.x * BT;
    const bf8* wsf = (const bf8*)ws;

    // ---- B-fragments from ws (coalesced dwordx4, L2-hit) ----
    bf8 bfr[5][2];
    #pragma unroll
    for (int nt = 0; nt < 5; ++nt)
        #pragma unroll
        for (int kt = 0; kt < 2; ++kt)
            bfr[nt][kt] = wsf[(FMB + nt*2 + kt)*64 + l];
    bf8 abot0 = wsf[(FAT + 0)*64 + l];
    bf8 abot1 = wsf[(FAT + 1)*64 + l];

    float bias1[4];
    #pragma unroll
    for (int nt = 0; nt < 4; ++nt) bias1[nt] = ue_b1[nt*16 + lr];
    const float aw2  = at_w2[lr];
    const float atb2 = at_b2[0];

    // ---- stage ieb + sidx ----
    {
        int bb = 4*w + lq;
        int item = item_inputs[bbase + bb];
        ((float4*)(ieb + bb*68))[lr] = ((const float4*)(item_emb + (size_t)item*64))[lr];
    }
    if (l < G_){
        #pragma unroll
        for (int i = 0; i < 4; ++i){
            int bb = 4*w + i;
            int gid = group_inputs[bbase + bb];
            sidx[bb*G_ + l] = group_members[gid*G_ + l];
        }
    }
    __syncthreads();

    // ---- tv GEMM (redundant per wave): tv[b][u] = ie[b] . at_w1[64:,u] ----
    f4 tvacc = (f4){0.f, 0.f, 0.f, 0.f};
    #pragma unroll
    for (int kt = 0; kt < 2; ++kt){
        const float* ap = ieb + lr*68 + kt*32 + lq*8;
        bf8 a = pack8(*(const float4*)ap, *(const float4*)(ap + 4));
        tvacc = __builtin_amdgcn_mfma_f32_16x16x32_bf16(a, kt ? abot1 : abot0, tvacc, 0, 0, 0);
    }
    const float atb1 = at_b1[lr];
    float tvi[4];
    #pragma unroll
    for (int i = 0; i < 4; ++i)
        tvi[i] = __shfl(tvacc[i], w*16 + lr) + atb1;   // tv[4w+i][lr]

    // ================= Phase 1: member GEMMs =================
    // remainder tile: rows = members 16..19 of this wave's 4 batches
    float rem[4];
    {
        int sx = sidx[(4*w + (lr >> 2))*G_ + 16 + (lr & 3)];
        const float4* p = (const float4*)(user_emb + (size_t)sx*64) + lq*2;
        bf8 a0 = pack8(p[0], p[1]);
        bf8 a1 = pack8(p[8], p[9]);
        f4 acc[5];
        #pragma unroll
        for (int nt = 0; nt < 5; ++nt) acc[nt] = (f4){0.f, 0.f, 0.f, 0.f};
        #pragma unroll
        for (int nt = 0; nt < 5; ++nt){
            acc[nt] = __builtin_amdgcn_mfma_f32_16x16x32_bf16(a0, bfr[nt][0], acc[nt], 0, 0, 0);
            acc[nt] = __builtin_amdgcn_mfma_f32_16x16x32_bf16(a1, bfr[nt][1], acc[nt], 0, 0, 0);
        }
        #pragma unroll
        for (int nt = 0; nt < 4; ++nt){
            float rs = 0.f;
            #pragma unroll
            for (int rr = 0; rr < 4; ++rr) rs += fmaxf(acc[nt][rr] + bias1[nt], 0.f);
            rem[nt] = rs;                               // batch 4w+lq, members 16..19, col nt*16+lr
        }
        float tvq = (lq == 0) ? tvi[0] : (lq == 1) ? tvi[1] : (lq == 2) ? tvi[2] : tvi[3];
        float vv[4];
        #pragma unroll
        for (int rr = 0; rr < 4; ++rr) vv[rr] = fmaxf(acc[4][rr] + tvq, 0.f) * aw2;
        #pragma unroll
        for (int rr = 0; rr < 4; ++rr){
            vv[rr] += __shfl_xor(vv[rr], 1, 16);
            vv[rr] += __shfl_xor(vv[rr], 2, 16);
            vv[rr] += __shfl_xor(vv[rr], 4, 16);
            vv[rr] += __shfl_xor(vv[rr], 8, 16);
        }
        if (lr == 0){
            #pragma unroll
            for (int rr = 0; rr < 4; ++rr)
                wsm[(4*w + lq)*G_ + 16 + rr] = vv[rr] + atb2;
        }
    }

    // main tiles: batch 4w+i, members 0..15
    #pragma unroll 1
    for (int i = 0; i < 4; ++i){
        const int bb = 4*w + i;
        const int sx = sidx[bb*G_ + lr];
        const float4* p = (const float4*)(user_emb + (size_t)sx*64) + lq*2;
        bf8 a0 = pack8(p[0], p[1]);
        bf8 a1 = pack8(p[8], p[9]);
        f4 acc[5];
        #pragma unroll
        for (int nt = 0; nt < 5; ++nt) acc[nt] = (f4){0.f, 0.f, 0.f, 0.f};
        #pragma unroll
        for (int nt = 0; nt < 5; ++nt){
            acc[nt] = __builtin_amdgcn_mfma_f32_16x16x32_bf16(a0, bfr[nt][0], acc[nt], 0, 0, 0);
            acc[nt] = __builtin_amdgcn_mfma_f32_16x16x32_bf16(a1, bfr[nt][1], acc[nt], 0, 0, 0);
        }
        // mean of relu-hidden (members 0..15 + remainder injection in quarter i)
        #pragma unroll
        for (int nt = 0; nt < 4; ++nt){
            float rs = 0.f;
            #pragma unroll
            for (int rr = 0; rr < 4; ++rr) rs += fmaxf(acc[nt][rr] + bias1[nt], 0.f);
            if (lq == i) rs += rem[nt];
            rs += __shfl_xor(rs, 16);
            rs += __shfl_xor(rs, 32);
            if (lq == nt) xAh[bb*136 + nt*16 + lr] = cvt1(rs * (1.f / G_));
        }
        // scores members 0..15
        {
            float vv[4];
            #pragma unroll
            for (int rr = 0; rr < 4; ++rr) vv[rr] = fmaxf(acc[4][rr] + tvi[i], 0.f) * aw2;
            #pragma unroll
            for (int rr = 0; rr < 4; ++rr){
                vv[rr] += __shfl_xor(vv[rr], 1, 16);
                vv[rr] += __shfl_xor(vv[rr], 2, 16);
                vv[rr] += __shfl_xor(vv[rr], 4, 16);
                vv[rr] += __shfl_xor(vv[rr], 8, 16);
            }
            if (lr == 0){
                #pragma unroll
                for (int rr = 0; rr < 4; ++rr)
                    wsm[bb*G_ + 4*lq + rr] = vv[rr] + atb2;
            }
        }
        // softmax over 20 scores
        {
            float sval = (l < G_) ? wsm[bb*G_ + l] : -3.0e38f;
            float mx = sval;
            mx = fmaxf(mx, __shfl_xor(mx, 1, 32));
            mx = fmaxf(mx, __shfl_xor(mx, 2, 32));
            mx = fmaxf(mx, __shfl_xor(mx, 4, 32));
            mx = fmaxf(mx, __shfl_xor(mx, 8, 32));
            mx = fmaxf(mx, __shfl_xor(mx, 16, 32));
            float e = (l < G_) ? expf(sval - mx) : 0.f;
            float sm = e;
            sm += __shfl_xor(sm, 1, 32);
            sm += __shfl_xor(sm, 2, 32);
            sm += __shfl_xor(sm, 4, 32);
            sm += __shfl_xor(sm, 8, 32);
            sm += __shfl_xor(sm, 16, 32);
            if (l < G_) wsm[bb*G_ + l] = e / sm;
        }
        // attention-weighted member sum
        {
            float ga = 0.f;
            #pragma unroll
            for (int g = 0; g < G_; ++g)
                ga += wsm[bb*G_ + g] * user_emb[(size_t)sidx[bb*G_ + g]*64 + l];
            gefb[bb*64 + l] = ga;
        }
    }
    __syncthreads();

    // ================= Phase 2: group-MLP chain (M=16 batches) =================
    // L1: gz0 = relu(hbar @ ue_w2 + b2), 64 cols, wave w -> tile w
    {
        int col = w*16 + lr;
        f4 acc = (f4){0.f, 0.f, 0.f, 0.f};
        #pragma unroll
        for (int kt = 0; kt < 2; ++kt){
            bf8 a = *(const bf8*)(xAh + lr*136 + kt*32 + lq*8);
            acc = __builtin_amdgcn_mfma_f32_16x16x32_bf16(a, wsf[(FUE2 + w*2 + kt)*64 + l], acc, 0, 0, 0);
        }
        float bs = ue_b2[col];
        #pragma unroll
        for (int rr = 0; rr < 4; ++rr)
            xBh[(4*lq + rr)*136 + col] = cvt1(fmaxf(acc[rr] + bs, 0.f));
    }
    __syncthreads();
    // L2: t1 = relu(gz0 @ ge_w1 + b1), 96 cols
    for (int t = w; t < 6; t += 4){
        int col = t*16 + lr;
        f4 acc = (f4){0.f, 0.f, 0.f, 0.f};
        #pragma unroll
        for (int kt = 0; kt < 2; ++kt){
            bf8 a = *(const bf8*)(xBh + lr*136 + kt*32 + lq*8);
            acc = __builtin_amdgcn_mfma_f32_16x16x32_bf16(a, wsf[(FGE1 + t*2 + kt)*64 + l], acc, 0, 0, 0);
        }
        float bs = ge_b1[col];
        #pragma unroll
        for (int rr = 0; rr < 4; ++rr)
            xAh[(4*lq + rr)*136 + col] = cvt1(fmaxf(acc[rr] + bs, 0.f));
    }
    __syncthreads();
    // L3: x3 = t1 @ ge_w2 + b2, 128 cols (raw f32)
    for (int t = w; t < 8; t += 4){
        int col = t*16 + lr;
        f4 acc = (f4){0.f, 0.f, 0.f, 0.f};
        #pragma unroll
        for (int kt = 0; kt < 3; ++kt){
            bf8 a = *(const bf8*)(xAh + lr*136 + kt*32 + lq*8);
            acc = __builtin_amdgcn_mfma_f32_16x16x32_bf16(a, wsf[(FGE2 + t*3 + kt)*64 + l], acc, 0, 0, 0);
        }
        float bs = ge_b2[col];
        #pragma unroll
        for (int rr = 0; rr < 4; ++rr)
            x3u[(4*lq + rr)*132 + col] = acc[rr] + bs;
    }
    __syncthreads();

    // ================= Phase 3: reparameterize + predictor =================
    #pragma unroll
    for (int i = 0; i < 4; ++i){
        int bb = 4*w + i;
        float mu  = x3u[bb*132 + l];
        float sgr = x3u[bb*132 + 64 + l];
        float sg  = 0.1f + 0.9f / (1.f + expf(-sgr));
        gefb[bb*64 + l] += mu + sg * eps[(size_t)(bbase + bb)*64 + l];
    }
    __syncthreads();                        // all x3 reads done -> region reusable
    unsigned short* ncf = (unsigned short*)x3u;   // [16][200] bf16
    #pragma unroll
    for (int i = 0; i < 4; ++i){
        int bb = 4*w + i;
        float gef = gefb[bb*64 + l];
        float iev = ieb[bb*68 + l];
        ncf[bb*200 + l]       = cvt1(gef * iev);
        ncf[bb*200 + 64 + l]  = cvt1(gef);
        ncf[bb*200 + 128 + l] = cvt1(iev);
    }
    __syncthreads();
    if (w == 0){
        f4 acc = (f4){0.f, 0.f, 0.f, 0.f};
        #pragma unroll
        for (int kt = 0; kt < 6; ++kt){
            bf8 a = *(const bf8*)(ncf + lr*200 + kt*32 + lq*8);
            acc = __builtin_amdgcn_mfma_f32_16x16x32_bf16(a, wsf[(FPR + kt)*64 + l], acc, 0, 0, 0);
        }
        float pb1 = (lr < 8) ? pr_b1[lr] : 0.f;
        float pw2 = (lr < 8) ? pr_w2[lr] : 0.f;
        float pb2 = pr_b2[0];
        float vv[4];
        #pragma unroll
        for (int rr = 0; rr < 4; ++rr) vv[rr] = fmaxf(acc[rr] + pb1, 0.f) * pw2;
        #pragma unroll
        for (int rr = 0; rr < 4; ++rr){
            vv[rr] += __shfl_xor(vv[rr], 1, 16);
            vv[rr] += __shfl_xor(vv[rr], 2, 16);
            vv[rr] += __shfl_xor(vv[rr], 4, 16);
            vv[rr] += __shfl_xor(vv[rr], 8, 16);
        }
        if (lr == 0){
            #pragma unroll
            for (int rr = 0; rr < 4; ++rr)
                out[bbase + 4*lq + rr] = 1.f / (1.f + expf(-(vv[rr] + pb2)));
        }
    }
}

extern "C" void kernel_launch(void* const* d_in, const int* in_sizes, int n_in,
                              void* d_out, int out_size, void* d_ws, size_t ws_size,
                              hipStream_t stream) {
    const int*   group_inputs  = (const int*)d_in[0];
    const int*   item_inputs   = (const int*)d_in[1];
    const int*   group_members = (const int*)d_in[2];
    const float* eps           = (const float*)d_in[3];
    const float* user_emb      = (const float*)d_in[4];
    const float* item_emb      = (const float*)d_in[5];
    const float* ue_w1 = (const float*)d_in[6];
    const float* ue_b1 = (const float*)d_in[7];
    const float* ue_w2 = (const float*)d_in[8];
    const float* ue_b2 = (const float*)d_in[9];
    const float* ge_w1 = (const float*)d_in[10];
    const float* ge_b1 = (const float*)d_in[11];
    const float* ge_w2 = (const float*)d_in[12];
    const float* ge_b2 = (const float*)d_in[13];
    const float* at_w1 = (const float*)d_in[14];
    const float* at_b1 = (const float*)d_in[15];
    const float* at_w2 = (const float*)d_in[16];
    const float* at_b2 = (const float*)d_in[17];
    const float* pr_w1 = (const float*)d_in[18];
    const float* pr_b1 = (const float*)d_in[19];
    const float* pr_w2 = (const float*)d_in[20];
    const float* pr_b2 = (const float*)d_in[21];
    float* out = (float*)d_out;
    unsigned short* ws = (unsigned short*)d_ws;

    vargr_prep<<<(FTOT*64 + 255)/256, 256, 0, stream>>>(
        ue_w1, ue_w2, ge_w1, ge_w2, at_w1, pr_w1, ws);

    const int nb = in_sizes[0];          // B = 16384, divisible by BT=16
    vargr_main<<<nb / BT, 256, 0, stream>>>(
        group_inputs, item_inputs, group_members, eps, user_emb, item_emb,
        ue_b1, ue_b2, ge_b1, ge_b2, at_b1, at_w2, at_b2, pr_b1, pr_w2, pr_b2,
        ws, out);
}